// Round 1
// baseline (606.576 us; speedup 1.0000x reference)
//
#include <hip/hip_runtime.h>
#include <hip/hip_fp16.h>
#include <hip/hip_bf16.h>

// Problem constants (from reference setup_inputs)
#define NC    32           // channels
#define NH1   256          // hidden dim
#define W_YX  727
#define H_YX  314
#define W_ZX  727
#define H_ZX  1300
#define W_ZY  314
#define H_ZY  1300
#define HW_YX (W_YX * H_YX)   // 228278
#define HW_ZX (W_ZX * H_ZX)   // 945100
#define HW_ZY (W_ZY * H_ZY)   // 408200

#define PSTRIDE 12         // dwords per point in parS  (12p%32: 2-way = free)
#define FSTRIDE 20         // dwords per point in featS (20p%32: 2-way, 16B-aligned)

typedef __attribute__((ext_vector_type(8))) short short8;   // 8 bf16 (4 VGPRs)
typedef __attribute__((ext_vector_type(4))) float f32x4;    // MFMA acc

// float -> bf16 (RNE), raw short (cold-path prep kernels)
__device__ __forceinline__ short f2bf(float f) {
    unsigned u = __float_as_uint(f);
    unsigned r = u + 0x7fffu + ((u >> 16) & 1u);
    return (short)(r >> 16);
}
// pack two floats -> bf16 pair (RNE; v_cvt_pk_bf16_f32 on gfx950)
__device__ __forceinline__ unsigned pk2(float a, float b) {
    union { __hip_bfloat162 h; unsigned u; } c;
    c.h = __float22bfloat162_rn(make_float2(a, b));
    return c.u;
}

// ---------------------------------------------------------------------------
// Transpose (C=32, HW) fp32 -> (HW, C=32) bf16.  LDS-free version:
// thread t owns channels [c8*8, c8*8+8) x hw [hw0 + (t>>2)*4, +4).
// Reads: 8x float4 (4 contiguous 256B segments per instr).
// Pack in-register (v_cvt_pk_bf16_f32), store 4x uint4 tiling dst.
// ---------------------------------------------------------------------------
__global__ __launch_bounds__(256) void kplane_transpose_bf16(
    const float* __restrict__ src, unsigned short* __restrict__ dst, int HW)
{
    int t  = threadIdx.x;
    int c8 = t & 3;            // channel group (8 channels)
    int r  = t >> 2;           // 0..63: hw sub-tile
    int hw0 = blockIdx.x * 256;
    int hwt = hw0 + r * 4;     // this thread's first hw

    if (hw0 + 256 <= HW) {
        float4 v[8];
#pragma unroll
        for (int cc = 0; cc < 8; ++cc) {
            int c = c8 * 8 + cc;
            v[cc] = *(const float4*)(src + (size_t)c * HW + hwt);
        }
#pragma unroll
        for (int k = 0; k < 4; ++k) {
            uint4 o;
            unsigned* ou = &o.x;
#pragma unroll
            for (int e = 0; e < 4; ++e) {
                const float* p0 = (const float*)&v[2 * e];
                const float* p1 = (const float*)&v[2 * e + 1];
                ou[e] = pk2(p0[k], p1[k]);
            }
            *(uint4*)(dst + (size_t)(hwt + k) * NC + c8 * 8) = o;
        }
    } else {
        // tail block: scalar guarded path
        for (int k = 0; k < 4; ++k) {
            int hw = hwt + k;
            if (hw < HW) {
                uint4 o;
                unsigned* ou = &o.x;
#pragma unroll
                for (int e = 0; e < 4; ++e) {
                    float a = src[(size_t)(c8 * 8 + 2 * e) * HW + hw];
                    float b = src[(size_t)(c8 * 8 + 2 * e + 1) * HW + hw];
                    ou[e] = pk2(a, b);
                }
                *(uint4*)(dst + (size_t)hw * NC + c8 * 8) = o;
            }
        }
    }
}

// ---------------------------------------------------------------------------
// w1 (32x256) -> bf16 A-fragment order for MFMA1 (A = w1^T, m=hidden, k=ch):
// w1a[(nt*64+lane)*8+j] = w1[ch=(lane>>4)*8+j][hid=nt*16+(lane&15)]
// ---------------------------------------------------------------------------
__global__ __launch_bounds__(256) void kplane_prep_w1a(
    const float* __restrict__ w1, short* __restrict__ w1a)
{
    int idx = blockIdx.x * 256 + threadIdx.x;   // 0..8191
    int j    = idx & 7;
    int lane = (idx >> 3) & 63;
    int nt   = idx >> 9;
    int ch  = (lane >> 4) * 8 + j;
    int hid = nt * 16 + (lane & 15);
    w1a[idx] = f2bf(w1[ch * NH1 + hid]);
}

// ---------------------------------------------------------------------------
// w2 (256x4) -> bf16 A-fragment order for MFMA2 (A = w2^T, m=o, k=hidden),
// hidden permutation matched to MFMA1's C-layout-as-B2 trick:
// k slot (kk,quad,j) <-> hidden = (2kk+(j>=4))*16 + quad*4 + (j&3)
// ---------------------------------------------------------------------------
__global__ __launch_bounds__(256) void kplane_prep_w2a(
    const float* __restrict__ w2, short* __restrict__ w2a)
{
    int idx = blockIdx.x * 256 + threadIdx.x;   // 0..4095
    int j    = idx & 7;
    int lane = (idx >> 3) & 63;
    int kk   = idx >> 9;
    int o    = lane & 15;
    int quad = lane >> 4;
    int hid  = (2 * kk + (j >> 2)) * 16 + quad * 4 + (j & 3);
    float v  = (o < 4) ? w2[hid * 4 + o] : 0.0f;
    w2a[idx] = f2bf(v);
}

// ---------------------------------------------------------------------------
// Bilinear setup: byte offsets of the two y-rows at x0 (x1 = +64B implicit;
// at the x-clamp edge wx==0 so the x1 half is weighted to zero).
// ---------------------------------------------------------------------------
__device__ __forceinline__ void bilin3(
    float gx, float gy, int W, int H,
    unsigned& o0, unsigned& o1, float& wx, float& wy)
{
    float ix  = (gx + 1.0f) * 0.5f * (float)(W - 1);
    float iy  = (gy + 1.0f) * 0.5f * (float)(H - 1);
    float x0f = floorf(ix), y0f = floorf(iy);
    wx = ix - x0f; wy = iy - y0f;
    int x0 = (int)x0f; x0 = x0 < 0 ? 0 : (x0 > W - 1 ? W - 1 : x0);
    int y0 = (int)y0f; y0 = y0 < 0 ? 0 : (y0 > H - 1 ? H - 1 : y0);
    int y1 = y0 + 1; if (y1 > H - 1) y1 = H - 1;
    o0 = (unsigned)(y0 * W + x0) * 64u;
    o1 = (unsigned)(y1 * W + x0) * 64u;
}

// Bilinear-combine 4 corner chunks (8 channels) fully in-lane.
template <bool FIRST>
__device__ __forceinline__ void corner4(
    const uint4& A, const uint4& B, const uint4& C, const uint4& D,
    float wx, float wy, float F[8])
{
    float w00 = (1.0f - wx) * (1.0f - wy);
    float w01 = wx * (1.0f - wy);
    float w10 = (1.0f - wx) * wy;
    float w11 = wx * wy;
    const unsigned* ua = &A.x; const unsigned* ub = &B.x;
    const unsigned* uc = &C.x; const unsigned* ud = &D.x;
#pragma unroll
    for (int e = 0; e < 4; ++e) {
        float a0 = __uint_as_float(ua[e] << 16);
        float a1 = __uint_as_float(ua[e] & 0xffff0000u);
        float b0 = __uint_as_float(ub[e] << 16);
        float b1 = __uint_as_float(ub[e] & 0xffff0000u);
        float c0 = __uint_as_float(uc[e] << 16);
        float c1 = __uint_as_float(uc[e] & 0xffff0000u);
        float d0 = __uint_as_float(ud[e] << 16);
        float d1 = __uint_as_float(ud[e] & 0xffff0000u);
        float v0 = w00 * a0; v0 = fmaf(w01, b0, v0);
        v0 = fmaf(w10, c0, v0); v0 = fmaf(w11, d0, v0);
        float v1 = w00 * a1; v1 = fmaf(w01, b1, v1);
        v1 = fmaf(w10, c1, v1); v1 = fmaf(w11, d1, v1);
        if (FIRST) { F[2 * e] = v0; F[2 * e + 1] = v1; }
        else       { F[2 * e] *= v0; F[2 * e + 1] *= v1; }
    }
}

// ---------------------------------------------------------------------------
// Fused kernel. Block = 256 threads = 256 points.
// Phase 0: 1 thread/point computes bilinear params -> LDS (12 dwords/pt).
// Phase 1: 4 lanes/point, 12 in-lane 16B corner loads, zero shuffles,
//          features packed bf16 -> LDS.
// Phase 2: MFMA1 (A=w1^T) -> relu+pack -> MFMA2 (A=w2^T) with a hidden
//          permutation that makes C1-layout == B2-layout. No reductions.
// ---------------------------------------------------------------------------
__global__ __launch_bounds__(256) void kplane_fused(
    const float* __restrict__ pts,
    const unsigned short* __restrict__ tyx,
    const unsigned short* __restrict__ tzx,
    const unsigned short* __restrict__ tzy,
    const short* __restrict__ w1a, const short* __restrict__ w2a,
    const float* __restrict__ b1, const float* __restrict__ b2,
    float* __restrict__ out)
{
    __shared__ unsigned parS[256 * PSTRIDE];    // 12 KB
    __shared__ unsigned featS[256 * FSTRIDE];   // 20 KB

    int t = threadIdx.x;
    int base = blockIdx.x * 256;

    // ---- phase 0: bilinear params for point `t` ---------------------------
    {
        float px = pts[(size_t)(base + t) * 3 + 0];
        float py = pts[(size_t)(base + t) * 3 + 1];
        float pz = pts[(size_t)(base + t) * 3 + 2];
        unsigned a0, a1, c0, c1, d0, d1;
        float awx, awy, cwx, cwy, dwx, dwy;
        bilin3(px, py, W_YX, H_YX, a0, a1, awx, awy);
        bilin3(px, pz, W_ZX, H_ZX, c0, c1, cwx, cwy);
        bilin3(py, pz, W_ZY, H_ZY, d0, d1, dwx, dwy);
        uint4* P = (uint4*)&parS[t * PSTRIDE];
        uint4 P0 = {a0, a1, c0, c1};
        uint4 P1 = {d0, d1, __float_as_uint(awx), __float_as_uint(awy)};
        uint4 P2 = {__float_as_uint(cwx), __float_as_uint(cwy),
                    __float_as_uint(dwx), __float_as_uint(dwy)};
        P[0] = P0; P[1] = P1; P[2] = P2;
    }
    __syncthreads();

    // ---- phase 1: gather, 4 lanes/point -----------------------------------
    {
        int q = t >> 2, j = t & 3;
        int jx16 = j * 16;
        const char* Byx = (const char*)tyx;
        const char* Bzx = (const char*)tzx;
        const char* Bzy = (const char*)tzy;
#pragma unroll
        for (int r = 0; r < 4; ++r) {
            int p = r * 64 + q;
            const uint4* P = (const uint4*)&parS[p * PSTRIDE];
            uint4 P0 = P[0], P1 = P[1], P2 = P[2];
            float awx = __uint_as_float(P1.z), awy = __uint_as_float(P1.w);
            float cwx = __uint_as_float(P2.x), cwy = __uint_as_float(P2.y);
            float dwx = __uint_as_float(P2.z), dwy = __uint_as_float(P2.w);

            // 12 independent 16B loads (all issued before use)
            uint4 La = *(const uint4*)(Byx + P0.x + jx16);
            uint4 Lb = *(const uint4*)(Byx + P0.x + 64 + jx16);
            uint4 Lc = *(const uint4*)(Byx + P0.y + jx16);
            uint4 Ld = *(const uint4*)(Byx + P0.y + 64 + jx16);
            uint4 Ma = *(const uint4*)(Bzx + P0.z + jx16);
            uint4 Mb = *(const uint4*)(Bzx + P0.z + 64 + jx16);
            uint4 Mc = *(const uint4*)(Bzx + P0.w + jx16);
            uint4 Md = *(const uint4*)(Bzx + P0.w + 64 + jx16);
            uint4 Na = *(const uint4*)(Bzy + P1.x + jx16);
            uint4 Nb = *(const uint4*)(Bzy + P1.x + 64 + jx16);
            uint4 Nc = *(const uint4*)(Bzy + P1.y + jx16);
            uint4 Nd = *(const uint4*)(Bzy + P1.y + 64 + jx16);

            float F[8];
            corner4<true >(La, Lb, Lc, Ld, awx, awy, F);
            corner4<false>(Ma, Mb, Mc, Md, cwx, cwy, F);
            corner4<false>(Na, Nb, Nc, Nd, dwx, dwy, F);

            uint4 o;
            o.x = pk2(F[0], F[1]); o.y = pk2(F[2], F[3]);
            o.z = pk2(F[4], F[5]); o.w = pk2(F[6], F[7]);
            *(uint4*)&featS[p * FSTRIDE + j * 4] = o;
        }
    }
    __syncthreads();

    // ---- phase 2: MFMA1 -> relu/pack -> MFMA2 -----------------------------
    {
        int w = t >> 6, lane = t & 63;
        int quad = lane >> 4, l15 = lane & 15;
        const short8* W1A = (const short8*)w1a;
        const short8* W2A = (const short8*)w2a;
        const float4* B1v = (const float4*)b1;
        float b20 = b2[0], b21 = b2[1], b22 = b2[2], b23 = b2[3];

#pragma unroll
        for (int mt = 0; mt < 4; ++mt) {
            int pt = w * 64 + mt * 16 + l15;
            union { uint4 v; short8 s; } bf;
            bf.v = *(const uint4*)&featS[pt * FSTRIDE + quad * 4];

            f32x4 acc = {0.f, 0.f, 0.f, 0.f};
#pragma unroll
            for (int kk = 0; kk < 8; ++kk) {
                float4 be = B1v[(2 * kk) * 4 + quad];
                float4 bo = B1v[(2 * kk + 1) * 4 + quad];
                f32x4 ze = {be.x, be.y, be.z, be.w};
                f32x4 zo = {bo.x, bo.y, bo.z, bo.w};
                ze = __builtin_amdgcn_mfma_f32_16x16x32_bf16(
                         W1A[(2 * kk) * 64 + lane], bf.s, ze, 0, 0, 0);
                zo = __builtin_amdgcn_mfma_f32_16x16x32_bf16(
                         W1A[(2 * kk + 1) * 64 + lane], bf.s, zo, 0, 0, 0);
                union { unsigned u[4]; short8 s; } hb;
                hb.u[0] = pk2(fmaxf(ze[0], 0.f), fmaxf(ze[1], 0.f));
                hb.u[1] = pk2(fmaxf(ze[2], 0.f), fmaxf(ze[3], 0.f));
                hb.u[2] = pk2(fmaxf(zo[0], 0.f), fmaxf(zo[1], 0.f));
                hb.u[3] = pk2(fmaxf(zo[2], 0.f), fmaxf(zo[3], 0.f));
                acc = __builtin_amdgcn_mfma_f32_16x16x32_bf16(
                          W2A[kk * 64 + lane], hb.s, acc, 0, 0, 0);
            }
            if (quad == 0) {
                float4 o = {acc[0] + b20, acc[1] + b21, acc[2] + b22, acc[3] + b23};
                ((float4*)out)[base + w * 64 + mt * 16 + l15] = o;
            }
        }
    }
}

// ---------------------------------------------------------------------------
// Fallback path (ws too small / N%256): direct (C,H,W) gather, VALU MLP.
// ---------------------------------------------------------------------------
__device__ __forceinline__ void bilin_full(
    float gx, float gy, int W, int H,
    int& o00, int& o01, int& o10, int& o11,
    float& w00, float& w01, float& w10, float& w11)
{
    float ix  = (gx + 1.0f) * 0.5f * (float)(W - 1);
    float iy  = (gy + 1.0f) * 0.5f * (float)(H - 1);
    float x0f = floorf(ix), y0f = floorf(iy);
    float wx  = ix - x0f,   wy  = iy - y0f;
    int x0 = (int)x0f; x0 = x0 < 0 ? 0 : (x0 > W - 1 ? W - 1 : x0);
    int y0 = (int)y0f; y0 = y0 < 0 ? 0 : (y0 > H - 1 ? H - 1 : y0);
    int x1 = x0 + 1; if (x1 > W - 1) x1 = W - 1;
    int y1 = y0 + 1; if (y1 > H - 1) y1 = H - 1;
    o00 = y0 * W + x0; o01 = y0 * W + x1;
    o10 = y1 * W + x0; o11 = y1 * W + x1;
    w00 = (1.0f - wx) * (1.0f - wy);
    w01 = wx * (1.0f - wy);
    w10 = (1.0f - wx) * wy;
    w11 = wx * wy;
}

__global__ __launch_bounds__(256) void kplane_fused_direct(
    const float* __restrict__ pts,
    const float* __restrict__ pyx, const float* __restrict__ pzx,
    const float* __restrict__ pzy,
    const float* __restrict__ w1, const float* __restrict__ b1,
    const float* __restrict__ w2, const float* __restrict__ b2,
    float* __restrict__ out, int N)
{
    int i = blockIdx.x * blockDim.x + threadIdx.x;
    if (i >= N) return;
    float px = pts[(size_t)i * 3 + 0];
    float py = pts[(size_t)i * 3 + 1];
    float pz = pts[(size_t)i * 3 + 2];

    int a00, a01, a10, a11; float aw00, aw01, aw10, aw11;
    int c00, c01, c10, c11; float cw00, cw01, cw10, cw11;
    int d00, d01, d10, d11; float dw00, dw01, dw10, dw11;
    bilin_full(px, py, W_YX, H_YX, a00, a01, a10, a11, aw00, aw01, aw10, aw11);
    bilin_full(px, pz, W_ZX, H_ZX, c00, c01, c10, c11, cw00, cw01, cw10, cw11);
    bilin_full(py, pz, W_ZY, H_ZY, d00, d01, d10, d11, dw00, dw01, dw10, dw11);

    float feat[NC];
#pragma unroll 4
    for (int c = 0; c < NC; ++c) {
        const float* byx = pyx + (size_t)c * HW_YX;
        const float* bzx = pzx + (size_t)c * HW_ZX;
        const float* bzy = pzy + (size_t)c * HW_ZY;
        float fyx = aw00 * byx[a00] + aw01 * byx[a01] + aw10 * byx[a10] + aw11 * byx[a11];
        float fzx = cw00 * bzx[c00] + cw01 * bzx[c01] + cw10 * bzx[c10] + cw11 * bzx[c11];
        float fzy = dw00 * bzy[d00] + dw01 * bzy[d01] + dw10 * bzy[d10] + dw11 * bzy[d11];
        feat[c] = fyx * fzx * fzy;
    }
    float o0 = b2[0], o1 = b2[1], o2 = b2[2], o3 = b2[3];
#pragma unroll 4
    for (int k = 0; k < NH1; ++k) {
        float hk = b1[k];
#pragma unroll
        for (int c = 0; c < NC; ++c)
            hk = fmaf(feat[c], w1[c * NH1 + k], hk);
        hk = fmaxf(hk, 0.0f);
        o0 = fmaf(hk, w2[k * 4 + 0], o0);
        o1 = fmaf(hk, w2[k * 4 + 1], o1);
        o2 = fmaf(hk, w2[k * 4 + 2], o2);
        o3 = fmaf(hk, w2[k * 4 + 3], o3);
    }
    float4 o; o.x = o0; o.y = o1; o.z = o2; o.w = o3;
    reinterpret_cast<float4*>(out)[i] = o;
}

// ---------------------------------------------------------------------------
extern "C" void kernel_launch(void* const* d_in, const int* in_sizes, int n_in,
                              void* d_out, int out_size, void* d_ws, size_t ws_size,
                              hipStream_t stream)
{
    const float* pts = (const float*)d_in[0];
    const float* pyx = (const float*)d_in[1];
    const float* pzx = (const float*)d_in[2];
    const float* pzy = (const float*)d_in[3];
    const float* w1  = (const float*)d_in[4];
    const float* b1  = (const float*)d_in[5];
    const float* w2  = (const float*)d_in[6];
    const float* b2  = (const float*)d_in[7];
    float* out = (float*)d_out;

    int N = in_sizes[0] / 3;

    size_t planes_e = (size_t)(HW_YX + HW_ZX + HW_ZY) * NC;  // bf16 elements
    size_t need = (planes_e + 8192 + 4096) * sizeof(short) + 256;

    if (ws_size >= need && (N % 256) == 0) {
        unsigned short* tyx = (unsigned short*)d_ws;
        unsigned short* tzx = tyx + (size_t)HW_YX * NC;
        unsigned short* tzy = tzx + (size_t)HW_ZX * NC;
        short* w1a = (short*)(tzy + (size_t)HW_ZY * NC);
        short* w2a = w1a + 8192;
        kplane_transpose_bf16<<<(HW_YX + 255) / 256, 256, 0, stream>>>(pyx, tyx, HW_YX);
        kplane_transpose_bf16<<<(HW_ZX + 255) / 256, 256, 0, stream>>>(pzx, tzx, HW_ZX);
        kplane_transpose_bf16<<<(HW_ZY + 255) / 256, 256, 0, stream>>>(pzy, tzy, HW_ZY);
        kplane_prep_w1a<<<32, 256, 0, stream>>>(w1, w1a);
        kplane_prep_w2a<<<16, 256, 0, stream>>>(w2, w2a);
        kplane_fused<<<N / 256, 256, 0, stream>>>(pts, tyx, tzx, tzy,
                                                  w1a, w2a, b1, b2, out);
    } else {
        int blocks = (N + 255) / 256;
        kplane_fused_direct<<<blocks, 256, 0, stream>>>(pts, pyx, pzx, pzy,
                                                        w1, b1, w2, b2, out, N);
    }
}

// Round 2
// 581.283 us; speedup vs baseline: 1.0435x; 1.0435x over previous
//
#include <hip/hip_runtime.h>
#include <hip/hip_fp16.h>
#include <hip/hip_bf16.h>

// Problem constants (from reference setup_inputs)
#define NC    32           // channels
#define NH1   256          // hidden dim
#define W_YX  727
#define H_YX  314
#define W_ZX  727
#define H_ZX  1300
#define W_ZY  314
#define H_ZY  1300
#define HW_YX (W_YX * H_YX)   // 228278
#define HW_ZX (W_ZX * H_ZX)   // 945100
#define HW_ZY (W_ZY * H_ZY)   // 408200

// merged prep-kernel block partition
#define NBW1  32                         // w1a: 8192 elems
#define NBW2  16                         // w2a: 4096 elems
#define NB_YX ((HW_YX + 255) / 256)      // 892
#define NB_ZX ((HW_ZX + 255) / 256)      // 3692
#define NB_ZY ((HW_ZY + 255) / 256)      // 1595
#define NB_PREP (NBW1 + NBW2 + NB_YX + NB_ZX + NB_ZY)

#define PSTRIDE 12         // dwords per point in parS  (12p%32: 2-way = free)
#define FSTRIDE 20         // dwords per point in featS (20p%32: 2-way, 16B-aligned)

typedef __attribute__((ext_vector_type(8))) short short8;   // 8 bf16 (4 VGPRs)
typedef __attribute__((ext_vector_type(4))) float f32x4;    // MFMA acc / nt-io

// float -> bf16 (RNE), raw short (cold-path prep)
__device__ __forceinline__ short f2bf(float f) {
    unsigned u = __float_as_uint(f);
    unsigned r = u + 0x7fffu + ((u >> 16) & 1u);
    return (short)(r >> 16);
}
// pack two floats -> bf16 pair (RNE; v_cvt_pk_bf16_f32 on gfx950)
__device__ __forceinline__ unsigned pk2(float a, float b) {
    union { __hip_bfloat162 h; unsigned u; } c;
    c.h = __float22bfloat162_rn(make_float2(a, b));
    return c.u;
}

// nontemporal 16B load (keep streaming fp32 source out of L2/L3 retention)
__device__ __forceinline__ f32x4 ntload4(const float* p) {
    return __builtin_nontemporal_load((const f32x4*)p);
}
__device__ __forceinline__ float ntload1(const float* p) {
    return __builtin_nontemporal_load(p);
}

// ---------------------------------------------------------------------------
// Transpose body: (C=32, HW) fp32 -> (HW, C=32) bf16, 256 hw per block.
// thread t owns channels [c8*8, c8*8+8) x hw [hw0 + (t>>2)*4, +4).
// Reads nontemporal (don't evict the bf16 planes the fused kernel needs).
// ---------------------------------------------------------------------------
__device__ __forceinline__ void transpose_body(
    const float* __restrict__ src, unsigned short* __restrict__ dst,
    int HW, int hw0, int t)
{
    int c8 = t & 3;            // channel group (8 channels)
    int r  = t >> 2;           // 0..63: hw sub-tile
    int hwt = hw0 + r * 4;     // this thread's first hw

    if (hw0 + 256 <= HW) {
        f32x4 v[8];
#pragma unroll
        for (int cc = 0; cc < 8; ++cc) {
            int c = c8 * 8 + cc;
            v[cc] = ntload4(src + (size_t)c * HW + hwt);
        }
#pragma unroll
        for (int k = 0; k < 4; ++k) {
            uint4 o;
            unsigned* ou = &o.x;
#pragma unroll
            for (int e = 0; e < 4; ++e)
                ou[e] = pk2(v[2 * e][k], v[2 * e + 1][k]);
            *(uint4*)(dst + (size_t)(hwt + k) * NC + c8 * 8) = o;
        }
    } else {
        // tail block: scalar guarded path (cold)
        for (int k = 0; k < 4; ++k) {
            int hw = hwt + k;
            if (hw < HW) {
                uint4 o;
                unsigned* ou = &o.x;
#pragma unroll
                for (int e = 0; e < 4; ++e) {
                    float a = src[(size_t)(c8 * 8 + 2 * e) * HW + hw];
                    float b = src[(size_t)(c8 * 8 + 2 * e + 1) * HW + hw];
                    ou[e] = pk2(a, b);
                }
                *(uint4*)(dst + (size_t)hw * NC + c8 * 8) = o;
            }
        }
    }
}

// ---------------------------------------------------------------------------
// ONE prep dispatch: w1a fragment prep, w2a fragment prep, 3 plane transposes.
//   blocks [0,NBW1)                : w1a
//   blocks [NBW1,NBW1+NBW2)        : w2a
//   remaining                      : plane transposes (YX, ZX, ZY)
// w1a[(nt*64+lane)*8+j] = w1[ch=(lane>>4)*8+j][hid=nt*16+(lane&15)]
// w2a k slot (kk,quad,j) <-> hidden = (2kk+(j>=4))*16 + quad*4 + (j&3)
// ---------------------------------------------------------------------------
__global__ __launch_bounds__(256) void kplane_prep_all(
    const float* __restrict__ pyx, const float* __restrict__ pzx,
    const float* __restrict__ pzy,
    const float* __restrict__ w1, const float* __restrict__ w2,
    unsigned short* __restrict__ tyx, unsigned short* __restrict__ tzx,
    unsigned short* __restrict__ tzy,
    short* __restrict__ w1a, short* __restrict__ w2a)
{
    int b = blockIdx.x;
    int t = threadIdx.x;

    if (b < NBW1) {                                 // ---- w1a ----
        int idx = b * 256 + t;                      // 0..8191
        int j    = idx & 7;
        int lane = (idx >> 3) & 63;
        int nt   = idx >> 9;
        int ch  = (lane >> 4) * 8 + j;
        int hid = nt * 16 + (lane & 15);
        w1a[idx] = f2bf(w1[ch * NH1 + hid]);
        return;
    }
    b -= NBW1;
    if (b < NBW2) {                                 // ---- w2a ----
        int idx = b * 256 + t;                      // 0..4095
        int j    = idx & 7;
        int lane = (idx >> 3) & 63;
        int kk   = idx >> 9;
        int o    = lane & 15;
        int quad = lane >> 4;
        int hid  = (2 * kk + (j >> 2)) * 16 + quad * 4 + (j & 3);
        float v  = (o < 4) ? w2[hid * 4 + o] : 0.0f;
        w2a[idx] = f2bf(v);
        return;
    }
    b -= NBW2;
    const float* src; unsigned short* dst; int HW;
    if (b < NB_YX)              { src = pyx; dst = tyx; HW = HW_YX; }
    else if (b < NB_YX + NB_ZX) { b -= NB_YX; src = pzx; dst = tzx; HW = HW_ZX; }
    else                        { b -= NB_YX + NB_ZX; src = pzy; dst = tzy; HW = HW_ZY; }
    transpose_body(src, dst, HW, b * 256, t);
}

// ---------------------------------------------------------------------------
// Bilinear setup: byte offsets of the two y-rows at x0 (x1 = +64B implicit;
// at the x-clamp edge wx==0 so the x1 half is weighted to zero).
// ---------------------------------------------------------------------------
__device__ __forceinline__ void bilin3(
    float gx, float gy, int W, int H,
    unsigned& o0, unsigned& o1, float& wx, float& wy)
{
    float ix  = (gx + 1.0f) * 0.5f * (float)(W - 1);
    float iy  = (gy + 1.0f) * 0.5f * (float)(H - 1);
    float x0f = floorf(ix), y0f = floorf(iy);
    wx = ix - x0f; wy = iy - y0f;
    int x0 = (int)x0f; x0 = x0 < 0 ? 0 : (x0 > W_YX - 1 ? W - 1 : x0);
    x0 = x0 > W - 1 ? W - 1 : x0;
    int y0 = (int)y0f; y0 = y0 < 0 ? 0 : (y0 > H - 1 ? H - 1 : y0);
    int y1 = y0 + 1; if (y1 > H - 1) y1 = H - 1;
    o0 = (unsigned)(y0 * W + x0) * 64u;
    o1 = (unsigned)(y1 * W + x0) * 64u;
}

// Bilinear-combine 4 corner chunks (8 channels) fully in-lane.
template <bool FIRST>
__device__ __forceinline__ void corner4(
    const uint4& A, const uint4& B, const uint4& C, const uint4& D,
    float wx, float wy, float F[8])
{
    float w00 = (1.0f - wx) * (1.0f - wy);
    float w01 = wx * (1.0f - wy);
    float w10 = (1.0f - wx) * wy;
    float w11 = wx * wy;
    const unsigned* ua = &A.x; const unsigned* ub = &B.x;
    const unsigned* uc = &C.x; const unsigned* ud = &D.x;
#pragma unroll
    for (int e = 0; e < 4; ++e) {
        float a0 = __uint_as_float(ua[e] << 16);
        float a1 = __uint_as_float(ua[e] & 0xffff0000u);
        float b0 = __uint_as_float(ub[e] << 16);
        float b1 = __uint_as_float(ub[e] & 0xffff0000u);
        float c0 = __uint_as_float(uc[e] << 16);
        float c1 = __uint_as_float(uc[e] & 0xffff0000u);
        float d0 = __uint_as_float(ud[e] << 16);
        float d1 = __uint_as_float(ud[e] & 0xffff0000u);
        float v0 = w00 * a0; v0 = fmaf(w01, b0, v0);
        v0 = fmaf(w10, c0, v0); v0 = fmaf(w11, d0, v0);
        float v1 = w00 * a1; v1 = fmaf(w01, b1, v1);
        v1 = fmaf(w10, c1, v1); v1 = fmaf(w11, d1, v1);
        if (FIRST) { F[2 * e] = v0; F[2 * e + 1] = v1; }
        else       { F[2 * e] *= v0; F[2 * e + 1] *= v1; }
    }
}

// ---------------------------------------------------------------------------
// Fused kernel. Block = 256 threads = 256 points.
// Phase 0: 1 thread/point computes bilinear params -> LDS (12 dwords/pt).
// Phase 1: 4 lanes/point, 12 in-lane 16B corner loads, zero shuffles,
//          features packed bf16 -> LDS.
// Phase 2: MFMA1 (A=w1^T) -> relu+pack -> MFMA2 (A=w2^T) with a hidden
//          permutation that makes C1-layout == B2-layout. No reductions.
// ---------------------------------------------------------------------------
__global__ __launch_bounds__(256) void kplane_fused(
    const float* __restrict__ pts,
    const unsigned short* __restrict__ tyx,
    const unsigned short* __restrict__ tzx,
    const unsigned short* __restrict__ tzy,
    const short* __restrict__ w1a, const short* __restrict__ w2a,
    const float* __restrict__ b1, const float* __restrict__ b2,
    float* __restrict__ out)
{
    __shared__ unsigned parS[256 * PSTRIDE];    // 12 KB
    __shared__ unsigned featS[256 * FSTRIDE];   // 20 KB

    int t = threadIdx.x;
    int base = blockIdx.x * 256;

    // ---- phase 0: bilinear params for point `t` ---------------------------
    {
        float px = ntload1(&pts[(size_t)(base + t) * 3 + 0]);
        float py = ntload1(&pts[(size_t)(base + t) * 3 + 1]);
        float pz = ntload1(&pts[(size_t)(base + t) * 3 + 2]);
        unsigned a0, a1, c0, c1, d0, d1;
        float awx, awy, cwx, cwy, dwx, dwy;
        bilin3(px, py, W_YX, H_YX, a0, a1, awx, awy);
        bilin3(px, pz, W_ZX, H_ZX, c0, c1, cwx, cwy);
        bilin3(py, pz, W_ZY, H_ZY, d0, d1, dwx, dwy);
        uint4* P = (uint4*)&parS[t * PSTRIDE];
        uint4 P0 = {a0, a1, c0, c1};
        uint4 P1 = {d0, d1, __float_as_uint(awx), __float_as_uint(awy)};
        uint4 P2 = {__float_as_uint(cwx), __float_as_uint(cwy),
                    __float_as_uint(dwx), __float_as_uint(dwy)};
        P[0] = P0; P[1] = P1; P[2] = P2;
    }
    __syncthreads();

    // ---- phase 1: gather, 4 lanes/point -----------------------------------
    {
        int q = t >> 2, j = t & 3;
        int jx16 = j * 16;
        const char* Byx = (const char*)tyx;
        const char* Bzx = (const char*)tzx;
        const char* Bzy = (const char*)tzy;
#pragma unroll
        for (int r = 0; r < 4; ++r) {
            int p = r * 64 + q;
            const uint4* P = (const uint4*)&parS[p * PSTRIDE];
            uint4 P0 = P[0], P1 = P[1], P2 = P[2];
            float awx = __uint_as_float(P1.z), awy = __uint_as_float(P1.w);
            float cwx = __uint_as_float(P2.x), cwy = __uint_as_float(P2.y);
            float dwx = __uint_as_float(P2.z), dwy = __uint_as_float(P2.w);

            // 12 independent 16B loads (all issued before use)
            uint4 La = *(const uint4*)(Byx + P0.x + jx16);
            uint4 Lb = *(const uint4*)(Byx + P0.x + 64 + jx16);
            uint4 Lc = *(const uint4*)(Byx + P0.y + jx16);
            uint4 Ld = *(const uint4*)(Byx + P0.y + 64 + jx16);
            uint4 Ma = *(const uint4*)(Bzx + P0.z + jx16);
            uint4 Mb = *(const uint4*)(Bzx + P0.z + 64 + jx16);
            uint4 Mc = *(const uint4*)(Bzx + P0.w + jx16);
            uint4 Md = *(const uint4*)(Bzx + P0.w + 64 + jx16);
            uint4 Na = *(const uint4*)(Bzy + P1.x + jx16);
            uint4 Nb = *(const uint4*)(Bzy + P1.x + 64 + jx16);
            uint4 Nc = *(const uint4*)(Bzy + P1.y + jx16);
            uint4 Nd = *(const uint4*)(Bzy + P1.y + 64 + jx16);

            float F[8];
            corner4<true >(La, Lb, Lc, Ld, awx, awy, F);
            corner4<false>(Ma, Mb, Mc, Md, cwx, cwy, F);
            corner4<false>(Na, Nb, Nc, Nd, dwx, dwy, F);

            uint4 o;
            o.x = pk2(F[0], F[1]); o.y = pk2(F[2], F[3]);
            o.z = pk2(F[4], F[5]); o.w = pk2(F[6], F[7]);
            *(uint4*)&featS[p * FSTRIDE + j * 4] = o;
        }
    }
    __syncthreads();

    // ---- phase 2: MFMA1 -> relu/pack -> MFMA2 -----------------------------
    {
        int w = t >> 6, lane = t & 63;
        int quad = lane >> 4, l15 = lane & 15;
        const short8* W1A = (const short8*)w1a;
        const short8* W2A = (const short8*)w2a;
        const float4* B1v = (const float4*)b1;
        float b20 = b2[0], b21 = b2[1], b22 = b2[2], b23 = b2[3];

#pragma unroll
        for (int mt = 0; mt < 4; ++mt) {
            int pt = w * 64 + mt * 16 + l15;
            union { uint4 v; short8 s; } bf;
            bf.v = *(const uint4*)&featS[pt * FSTRIDE + quad * 4];

            f32x4 acc = {0.f, 0.f, 0.f, 0.f};
#pragma unroll
            for (int kk = 0; kk < 8; ++kk) {
                float4 be = B1v[(2 * kk) * 4 + quad];
                float4 bo = B1v[(2 * kk + 1) * 4 + quad];
                f32x4 ze = {be.x, be.y, be.z, be.w};
                f32x4 zo = {bo.x, bo.y, bo.z, bo.w};
                ze = __builtin_amdgcn_mfma_f32_16x16x32_bf16(
                         W1A[(2 * kk) * 64 + lane], bf.s, ze, 0, 0, 0);
                zo = __builtin_amdgcn_mfma_f32_16x16x32_bf16(
                         W1A[(2 * kk + 1) * 64 + lane], bf.s, zo, 0, 0, 0);
                union { unsigned u[4]; short8 s; } hb;
                hb.u[0] = pk2(fmaxf(ze[0], 0.f), fmaxf(ze[1], 0.f));
                hb.u[1] = pk2(fmaxf(ze[2], 0.f), fmaxf(ze[3], 0.f));
                hb.u[2] = pk2(fmaxf(zo[0], 0.f), fmaxf(zo[1], 0.f));
                hb.u[3] = pk2(fmaxf(zo[2], 0.f), fmaxf(zo[3], 0.f));
                acc = __builtin_amdgcn_mfma_f32_16x16x32_bf16(
                          W2A[kk * 64 + lane], hb.s, acc, 0, 0, 0);
            }
            if (quad == 0) {
                f32x4 o = {acc[0] + b20, acc[1] + b21, acc[2] + b22, acc[3] + b23};
                __builtin_nontemporal_store(
                    o, (f32x4*)out + (base + w * 64 + mt * 16 + l15));
            }
        }
    }
}

// ---------------------------------------------------------------------------
// Fallback path (ws too small / N%256): direct (C,H,W) gather, VALU MLP.
// ---------------------------------------------------------------------------
__device__ __forceinline__ void bilin_full(
    float gx, float gy, int W, int H,
    int& o00, int& o01, int& o10, int& o11,
    float& w00, float& w01, float& w10, float& w11)
{
    float ix  = (gx + 1.0f) * 0.5f * (float)(W - 1);
    float iy  = (gy + 1.0f) * 0.5f * (float)(H - 1);
    float x0f = floorf(ix), y0f = floorf(iy);
    float wx  = ix - x0f,   wy  = iy - y0f;
    int x0 = (int)x0f; x0 = x0 < 0 ? 0 : (x0 > W - 1 ? W - 1 : x0);
    int y0 = (int)y0f; y0 = y0 < 0 ? 0 : (y0 > H - 1 ? H - 1 : y0);
    int x1 = x0 + 1; if (x1 > W - 1) x1 = W - 1;
    int y1 = y0 + 1; if (y1 > H - 1) y1 = H - 1;
    o00 = y0 * W + x0; o01 = y0 * W + x1;
    o10 = y1 * W + x0; o11 = y1 * W + x1;
    w00 = (1.0f - wx) * (1.0f - wy);
    w01 = wx * (1.0f - wy);
    w10 = (1.0f - wx) * wy;
    w11 = wx * wy;
}

__global__ __launch_bounds__(256) void kplane_fused_direct(
    const float* __restrict__ pts,
    const float* __restrict__ pyx, const float* __restrict__ pzx,
    const float* __restrict__ pzy,
    const float* __restrict__ w1, const float* __restrict__ b1,
    const float* __restrict__ w2, const float* __restrict__ b2,
    float* __restrict__ out, int N)
{
    int i = blockIdx.x * blockDim.x + threadIdx.x;
    if (i >= N) return;
    float px = pts[(size_t)i * 3 + 0];
    float py = pts[(size_t)i * 3 + 1];
    float pz = pts[(size_t)i * 3 + 2];

    int a00, a01, a10, a11; float aw00, aw01, aw10, aw11;
    int c00, c01, c10, c11; float cw00, cw01, cw10, cw11;
    int d00, d01, d10, d11; float dw00, dw01, dw10, dw11;
    bilin_full(px, py, W_YX, H_YX, a00, a01, a10, a11, aw00, aw01, aw10, aw11);
    bilin_full(px, pz, W_ZX, H_ZX, c00, c01, c10, c11, cw00, cw01, cw10, cw11);
    bilin_full(py, pz, W_ZY, H_ZY, d00, d01, d10, d11, dw00, dw01, dw10, dw11);

    float feat[NC];
#pragma unroll 4
    for (int c = 0; c < NC; ++c) {
        const float* byx = pyx + (size_t)c * HW_YX;
        const float* bzx = pzx + (size_t)c * HW_ZX;
        const float* bzy = pzy + (size_t)c * HW_ZY;
        float fyx = aw00 * byx[a00] + aw01 * byx[a01] + aw10 * byx[a10] + aw11 * byx[a11];
        float fzx = cw00 * bzx[c00] + cw01 * bzx[c01] + cw10 * bzx[c10] + cw11 * bzx[c11];
        float fzy = dw00 * bzy[d00] + dw01 * bzy[d01] + dw10 * bzy[d10] + dw11 * bzy[d11];
        feat[c] = fyx * fzx * fzy;
    }
    float o0 = b2[0], o1 = b2[1], o2 = b2[2], o3 = b2[3];
#pragma unroll 4
    for (int k = 0; k < NH1; ++k) {
        float hk = b1[k];
#pragma unroll
        for (int c = 0; c < NC; ++c)
            hk = fmaf(feat[c], w1[c * NH1 + k], hk);
        hk = fmaxf(hk, 0.0f);
        o0 = fmaf(hk, w2[k * 4 + 0], o0);
        o1 = fmaf(hk, w2[k * 4 + 1], o1);
        o2 = fmaf(hk, w2[k * 4 + 2], o2);
        o3 = fmaf(hk, w2[k * 4 + 3], o3);
    }
    float4 o; o.x = o0; o.y = o1; o.z = o2; o.w = o3;
    reinterpret_cast<float4*>(out)[i] = o;
}

// ---------------------------------------------------------------------------
extern "C" void kernel_launch(void* const* d_in, const int* in_sizes, int n_in,
                              void* d_out, int out_size, void* d_ws, size_t ws_size,
                              hipStream_t stream)
{
    const float* pts = (const float*)d_in[0];
    const float* pyx = (const float*)d_in[1];
    const float* pzx = (const float*)d_in[2];
    const float* pzy = (const float*)d_in[3];
    const float* w1  = (const float*)d_in[4];
    const float* b1  = (const float*)d_in[5];
    const float* w2  = (const float*)d_in[6];
    const float* b2  = (const float*)d_in[7];
    float* out = (float*)d_out;

    int N = in_sizes[0] / 3;

    size_t planes_e = (size_t)(HW_YX + HW_ZX + HW_ZY) * NC;  // bf16 elements
    size_t need = (planes_e + 8192 + 4096) * sizeof(short) + 256;

    if (ws_size >= need && (N % 256) == 0) {
        unsigned short* tyx = (unsigned short*)d_ws;
        unsigned short* tzx = tyx + (size_t)HW_YX * NC;
        unsigned short* tzy = tzx + (size_t)HW_ZX * NC;
        short* w1a = (short*)(tzy + (size_t)HW_ZY * NC);
        short* w2a = w1a + 8192;
        kplane_prep_all<<<NB_PREP, 256, 0, stream>>>(pyx, pzx, pzy, w1, w2,
                                                     tyx, tzx, tzy, w1a, w2a);
        kplane_fused<<<N / 256, 256, 0, stream>>>(pts, tyx, tzx, tzy,
                                                  w1a, w2a, b1, b2, out);
    } else {
        int blocks = (N + 255) / 256;
        kplane_fused_direct<<<blocks, 256, 0, stream>>>(pts, pyx, pzx, pzy,
                                                        w1, b1, w2, b2, out, N);
    }
}